// Round 14
// baseline (291.749 us; speedup 1.0000x reference)
//
#include <hip/hip_runtime.h>
#include <hip/hip_fp16.h>
#include <math.h>

#define N_NODES 100000
#define N_EDGES 1600000
#define N_GRAPHS 64
#define NB 391        // buckets of 256 nodes: ceil(100000/256)
#define CAP 5504      // bucket slab capacity; E[bucket]=4096 -> huge margin

// ordered-uint encode for float atomicMax (monotone bijection)
__device__ __forceinline__ unsigned f2o(float f) {
    unsigned u = __float_as_uint(f);
    return (u & 0x80000000u) ? ~u : (u | 0x80000000u);
}
__device__ __forceinline__ float o2f(unsigned u) {
    return (u & 0x80000000u) ? __uint_as_float(u & 0x7fffffffu) : __uint_as_float(~u);
}

__device__ __forceinline__ void storeh8(__half* p, float4 v) {
    __half2 o0 = __floats2half2_rn(v.x, v.y);
    __half2 o1 = __floats2half2_rn(v.z, v.w);
    float2 ow;
    ((__half2*)&ow)[0] = o0;
    ((__half2*)&ow)[1] = o1;
    *(float2*)p = ow;
}

typedef _Float16 h2r __attribute__((ext_vector_type(2)));
typedef _Float16 h4  __attribute__((ext_vector_type(4)));
union HB { float4 f4; h2r h[4]; };
union H4 { float2 f2; h4 h; };     // 8B = 4 packed fp16

// ---------------- phase 1: bucket edges by dst>>8 into fixed slabs ----------------
__global__ __launch_bounds__(256) void bucket_kernel(const int* __restrict__ src, const int* __restrict__ dst,
                                                     int* __restrict__ bucketCursor, unsigned* __restrict__ ebuf) {
    __shared__ int hist[NB];
    __shared__ int cur[NB];
    int tid = threadIdx.x;
    for (int b = tid; b < NB; b += 256) hist[b] = 0;
    __syncthreads();
    int e0 = blockIdx.x * 3200;                    // 500 blocks x 3200 = 1.6M exactly
    for (int i = tid; i < 3200; i += 256) {
        int d = dst[e0 + i];
        atomicAdd(&hist[d >> 8], 1);
    }
    __syncthreads();
    for (int b = tid; b < NB; b += 256) {
        int h = hist[b];
        cur[b] = h ? atomicAdd(&bucketCursor[b], h) : 0;   // reserve contiguous range
    }
    __syncthreads();
    for (int i = tid; i < 3200; i += 256) {
        int d = dst[e0 + i];
        int s = src[e0 + i];
        int bu = d >> 8;
        int pos = atomicAdd(&cur[bu], 1);          // LDS cursor within reserved range
        if (pos < CAP)
            ebuf[(size_t)bu * CAP + pos] = ((unsigned)(d & 255) << 24) | (unsigned)s;
    }
}

// ---------------- phase 2: per-bucket CSR finalize, all in LDS ----------------
__global__ __launch_bounds__(256) void csr_kernel(const unsigned* __restrict__ ebuf,
                                                  const int* __restrict__ bucketCursor,
                                                  int* __restrict__ colb, int* __restrict__ rowptr,
                                                  int* __restrict__ cnt, float* __restrict__ dis) {
    __shared__ unsigned stage[CAP];
    __shared__ int c256[256], row256[256], cur256[256];
    int b = blockIdx.x;
    int tid = threadIdx.x;
    int M = bucketCursor[b];
    if (M > CAP) M = CAP;
    c256[tid] = 0;
    __syncthreads();
    const unsigned* eb = ebuf + (size_t)b * CAP;
    for (int i = tid; i < M; i += 256) atomicAdd(&c256[eb[i] >> 24], 1);
    __syncthreads();
    if (tid < 64) {                                 // wave 0: exclusive scan of 256 counters
        int c0 = c256[tid * 4], c1 = c256[tid * 4 + 1], c2 = c256[tid * 4 + 2], c3 = c256[tid * 4 + 3];
        int s = c0 + c1 + c2 + c3;
        int inc = s;
        #pragma unroll
        for (int o = 1; o < 64; o <<= 1) {
            int v = __shfl_up(inc, o, 64);
            if (tid >= o) inc += v;
        }
        int ex = inc - s;
        row256[tid * 4] = ex;
        row256[tid * 4 + 1] = ex + c0;
        row256[tid * 4 + 2] = ex + c0 + c1;
        row256[tid * 4 + 3] = ex + c0 + c1 + c2;
    }
    __syncthreads();
    cur256[tid] = row256[tid];
    int node = (b << 8) + tid;
    if (node < N_NODES) {
        int c = c256[tid];
        cnt[node] = c;
        dis[node] = rsqrtf((float)(c + 1));
        rowptr[node] = b * CAP + row256[tid];
    }
    __syncthreads();
    for (int i = tid; i < M; i += 256) {
        unsigned p = eb[i];
        int slot = atomicAdd(&cur256[p >> 24], 1);
        stage[slot] = p & 0xFFFFFFu;
    }
    __syncthreads();
    for (int i = tid; i < M; i += 256) colb[b * CAP + i] = (int)stage[i];
}

// ---------------- GEMM1 v3: register-blocked 4x4, fp16 LDS operands, fp32 acc;
//   epilogue writes feature-split halves hs1a (cols 0..15) / hs1b (cols 16..31)
__global__ __launch_bounds__(256) void gemm1_kernel(const float* __restrict__ x, const float* __restrict__ W1,
                                                    const float* __restrict__ dis,
                                                    __half* __restrict__ hs1a, __half* __restrict__ hs1b) {
    __shared__ __half xsh[128][136];   // 34 KB
    __shared__ __half wth[32][136];    // 8.5 KB (W1^T)
    int tid = threadIdx.x;
    int r0 = blockIdx.x * 128;
    for (int idx = tid; idx < 128 * 32; idx += 256) {
        int k = idx >> 5, j = idx & 31;
        wth[j][k] = __float2half_rn(W1[idx]);
    }
    for (int idx = tid; idx < 128 * 32; idx += 256) {
        int r = idx >> 5, c4 = idx & 31;
        int gr = r0 + r;
        float4 v = (gr < N_NODES) ? ((const float4*)x)[(size_t)gr * 32 + c4] : make_float4(0.f, 0.f, 0.f, 0.f);
        __half* p = &xsh[r][c4 * 4];
        *(__half2*)p       = __floats2half2_rn(v.x, v.y);
        *(__half2*)(p + 2) = __floats2half2_rn(v.z, v.w);
    }
    __syncthreads();
    int jg = tid & 7;       // cols 4jg .. 4jg+3
    int rg = tid >> 3;      // rows rg + 32*ri
    float acc[4][4];
    #pragma unroll
    for (int i = 0; i < 4; i++)
        #pragma unroll
        for (int j = 0; j < 4; j++) acc[i][j] = 0.f;
    for (int kc = 0; kc < 128; kc += 8) {
        HB xr[4], wr[4];
        #pragma unroll
        for (int ri = 0; ri < 4; ri++) xr[ri].f4 = *(const float4*)&xsh[rg + 32 * ri][kc];
        #pragma unroll
        for (int jj = 0; jj < 4; jj++) wr[jj].f4 = *(const float4*)&wth[jg * 4 + jj][kc];
        #pragma unroll
        for (int ri = 0; ri < 4; ri++) {
            #pragma unroll
            for (int jj = 0; jj < 4; jj++) {
                #pragma unroll
                for (int t = 0; t < 4; t++) {
#if defined(__has_builtin) && __has_builtin(__builtin_amdgcn_fdot2)
                    acc[ri][jj] = __builtin_amdgcn_fdot2(xr[ri].h[t], wr[jj].h[t], acc[ri][jj], false);
#else
                    acc[ri][jj] += (float)xr[ri].h[t][0] * (float)wr[jj].h[t][0]
                                 + (float)xr[ri].h[t][1] * (float)wr[jj].h[t][1];
#endif
                }
            }
        }
    }
    __half* hb = (jg < 4) ? hs1a : hs1b;
    int qc = (jg & 3) * 4;
    #pragma unroll
    for (int ri = 0; ri < 4; ri++) {
        int gr = r0 + rg + 32 * ri;
        if (gr < N_NODES) {
            float dr = dis[gr];
            float2 ow;
            ((__half2*)&ow)[0] = __floats2half2_rn(dr * acc[ri][0], dr * acc[ri][1]);
            ((__half2*)&ow)[1] = __floats2half2_rn(dr * acc[ri][2], dr * acc[ri][3]);
            *(float2*)&hb[(size_t)gr * 16 + qc] = ow;
        }
    }
}

// ---------------- aggL1 pass: 16-feature L2-resident gather (3.2 MB buffer);
//   lane=(half, es 0..7, q 0..3); 24 edges pre-issued; fp16 combine + 1 fp16
//   butterfly round (mask 4), then fp32 rounds (8,16).
//   out[r] = fp16( dis[r] * lrelu(dis[r]*(sum + self) + b1p) )   [16 fp16/row]
__global__ __launch_bounds__(256) void aggL1_kernel(const __half* __restrict__ in, const int* __restrict__ colb,
                                                    const int* __restrict__ rowptr, const int* __restrict__ cnt,
                                                    const float* __restrict__ dis, const float* __restrict__ b1p,
                                                    __half* __restrict__ out) {
    int tid = threadIdx.x;
    int wid = tid >> 6;
    int lane = tid & 63;
    int half = lane >> 5;        // row within iteration
    int es = (lane >> 2) & 7;    // edge slot 0..7
    int q = lane & 3;            // feature quad 0..3 (16 features)
    int w = blockIdx.x * 4 + wid;          // 25000 waves exactly
    int r0 = w * 4;

    H4 z; z.f2 = make_float2(0.f, 0.f);
    int r = r0 + half;
    int st = rowptr[r];
    int n = cnt[r];
    H4 pS = z, p0 = z, p1 = z, p2 = z;
    if (es == 0) pS.f2 = *(const float2*)(in + (size_t)r * 16 + q * 4);
    {
        int e0 = es, e1 = 8 + es, e2 = 16 + es;
        if (e0 < n) p0.f2 = *(const float2*)(in + (size_t)colb[st + e0] * 16 + q * 4);
        if (e1 < n) p1.f2 = *(const float2*)(in + (size_t)colb[st + e1] * 16 + q * 4);
        if (e2 < n) p2.f2 = *(const float2*)(in + (size_t)colb[st + e2] * 16 + q * 4);
    }
    #pragma unroll
    for (int i = 0; i < 2; i++) {
        int rA = r;
        int stA = st, nA = n;
        H4 rS = pS, v0 = p0, v1 = p1, v2 = p2;
        pS = z; p0 = z; p1 = z; p2 = z;
        if (i == 0) {                         // pre-issue iteration 1
            r = r0 + 2 + half;
            st = rowptr[r];
            n = cnt[r];
            if (es == 0) pS.f2 = *(const float2*)(in + (size_t)r * 16 + q * 4);
            int e0 = es, e1 = 8 + es, e2 = 16 + es;
            if (e0 < n) p0.f2 = *(const float2*)(in + (size_t)colb[st + e0] * 16 + q * 4);
            if (e1 < n) p1.f2 = *(const float2*)(in + (size_t)colb[st + e1] * 16 + q * 4);
            if (e2 < n) p2.f2 = *(const float2*)(in + (size_t)colb[st + e2] * 16 + q * 4);
        }
        H4 u; u.h = (rS.h + v0.h) + (v1.h + v2.h);
        for (int k = 24; k < nA; k += 8) {    // tail deg>24 (~2% rows), fp16
            int e0 = k + es;
            if (e0 < nA) { H4 t; t.f2 = *(const float2*)(in + (size_t)colb[stA + e0] * 16 + q * 4); u.h = u.h + t.h; }
        }
        // butterfly round 1 in packed fp16 (mask 4)
        H4 o;
        o.f2.x = __shfl_xor(u.f2.x, 4, 64);
        o.f2.y = __shfl_xor(u.f2.y, 4, 64);
        u.h = u.h + o.h;
        float4 a = make_float4((float)u.h.x, (float)u.h.y, (float)u.h.z, (float)u.h.w);
        #pragma unroll
        for (int m = 8; m <= 16; m <<= 1) {   // fp32 rounds (within 32-lane half)
            a.x += __shfl_xor(a.x, m, 64);
            a.y += __shfl_xor(a.y, m, 64);
            a.z += __shfl_xor(a.z, m, 64);
            a.w += __shfl_xor(a.w, m, 64);
        }
        if (es == 0) {
            float4 bv = *(const float4*)&b1p[q * 4];
            float dr = dis[rA];
            float4 v;
            v.x = dr * a.x + bv.x; v.y = dr * a.y + bv.y; v.z = dr * a.z + bv.z; v.w = dr * a.w + bv.w;
            v.x = v.x > 0.f ? v.x : 0.1f * v.x;
            v.y = v.y > 0.f ? v.y : 0.1f * v.y;
            v.z = v.z > 0.f ? v.z : 0.1f * v.z;
            v.w = v.w > 0.f ? v.w : 0.1f * v.w;
            v.x *= dr; v.y *= dr; v.z *= dr; v.w *= dr;
            storeh8(out + (size_t)rA * 16 + q * 4, v);
        }
    }
}

// ---------------- aggL2 pass: same gather structure; writes fp32 half-row into
//   interleaved agg32 (out pre-offset by pass*16; row stride 32 floats).
__global__ __launch_bounds__(256) void aggL2_kernel(const __half* __restrict__ in, const int* __restrict__ colb,
                                                    const int* __restrict__ rowptr, const int* __restrict__ cnt,
                                                    const float* __restrict__ dis,
                                                    float* __restrict__ out) {
    int tid = threadIdx.x;
    int wid = tid >> 6;
    int lane = tid & 63;
    int half = lane >> 5;
    int es = (lane >> 2) & 7;
    int q = lane & 3;
    int w = blockIdx.x * 4 + wid;          // 25000 waves exactly
    int r0 = w * 4;

    H4 z; z.f2 = make_float2(0.f, 0.f);
    int r = r0 + half;
    int st = rowptr[r];
    int n = cnt[r];
    H4 pS = z, p0 = z, p1 = z, p2 = z;
    if (es == 0) pS.f2 = *(const float2*)(in + (size_t)r * 16 + q * 4);
    {
        int e0 = es, e1 = 8 + es, e2 = 16 + es;
        if (e0 < n) p0.f2 = *(const float2*)(in + (size_t)colb[st + e0] * 16 + q * 4);
        if (e1 < n) p1.f2 = *(const float2*)(in + (size_t)colb[st + e1] * 16 + q * 4);
        if (e2 < n) p2.f2 = *(const float2*)(in + (size_t)colb[st + e2] * 16 + q * 4);
    }
    #pragma unroll
    for (int i = 0; i < 2; i++) {
        int rA = r;
        int stA = st, nA = n;
        H4 rS = pS, v0 = p0, v1 = p1, v2 = p2;
        pS = z; p0 = z; p1 = z; p2 = z;
        if (i == 0) {
            r = r0 + 2 + half;
            st = rowptr[r];
            n = cnt[r];
            if (es == 0) pS.f2 = *(const float2*)(in + (size_t)r * 16 + q * 4);
            int e0 = es, e1 = 8 + es, e2 = 16 + es;
            if (e0 < n) p0.f2 = *(const float2*)(in + (size_t)colb[st + e0] * 16 + q * 4);
            if (e1 < n) p1.f2 = *(const float2*)(in + (size_t)colb[st + e1] * 16 + q * 4);
            if (e2 < n) p2.f2 = *(const float2*)(in + (size_t)colb[st + e2] * 16 + q * 4);
        }
        H4 u; u.h = (rS.h + v0.h) + (v1.h + v2.h);
        for (int k = 24; k < nA; k += 8) {
            int e0 = k + es;
            if (e0 < nA) { H4 t; t.f2 = *(const float2*)(in + (size_t)colb[stA + e0] * 16 + q * 4); u.h = u.h + t.h; }
        }
        H4 o;
        o.f2.x = __shfl_xor(u.f2.x, 4, 64);
        o.f2.y = __shfl_xor(u.f2.y, 4, 64);
        u.h = u.h + o.h;
        float4 a = make_float4((float)u.h.x, (float)u.h.y, (float)u.h.z, (float)u.h.w);
        #pragma unroll
        for (int m = 8; m <= 16; m <<= 1) {
            a.x += __shfl_xor(a.x, m, 64);
            a.y += __shfl_xor(a.y, m, 64);
            a.z += __shfl_xor(a.z, m, 64);
            a.w += __shfl_xor(a.w, m, 64);
        }
        if (es == 0) {
            float dr = dis[rA];
            float4 ov = make_float4(dr * a.x, dr * a.y, dr * a.z, dr * a.w);
            *(float4*)&out[(size_t)rA * 32 + q * 4] = ov;
        }
    }
}

// ---------------- gemm2p: out = agg32 @ W2 + b2, fused global-max-pool ----------------
__global__ __launch_bounds__(256) void gemm2p_kernel(const float* __restrict__ agg32, const float* __restrict__ W2,
                                                     const float* __restrict__ b2, const int* __restrict__ batch,
                                                     unsigned* __restrict__ gbufu) {
    __shared__ float as1[64][32];    // 8 KB
    __shared__ float w2s[32][64];    // 8 KB
    __shared__ float red[4][64];
    int tid = threadIdx.x;
    int r0 = blockIdx.x * 64;
    for (int idx = tid; idx < 32 * 64; idx += 256) w2s[idx >> 6][idx & 63] = W2[idx];
    for (int idx = tid; idx < 64 * 8; idx += 256) {
        int rl = idx >> 3, qc = idx & 7;
        int gr = r0 + rl;
        float4 v = (gr < N_NODES) ? ((const float4*)agg32)[(size_t)gr * 8 + qc] : make_float4(0.f, 0.f, 0.f, 0.f);
        *(float4*)&as1[rl][qc * 4] = v;
    }
    __syncthreads();
    int j = tid & 63;
    int rq = tid >> 6;   // wave id 0..3
    float w2c[32];
    #pragma unroll
    for (int k = 0; k < 32; k++) w2c[k] = w2s[k][j];
    float bj = b2[j];
    int rend = (r0 + 64 <= N_NODES) ? 64 : (N_NODES - r0);
    int gfirst = batch[r0];
    int glast = batch[r0 + rend - 1];
    bool uni = (gfirst == glast);    // block-uniform condition
    float runmax = -INFINITY;
    for (int i = 0; i < 16; i++) {
        int rl = rq + i * 4;
        if (rl >= rend) break;
        float acc = bj;
        #pragma unroll
        for (int kc = 0; kc < 32; kc += 4) {
            float4 av = *(const float4*)&as1[rl][kc];
            acc += av.x * w2c[kc] + av.y * w2c[kc + 1] + av.z * w2c[kc + 2] + av.w * w2c[kc + 3];
        }
        if (uni) runmax = fmaxf(runmax, acc);
        else atomicMax(&gbufu[batch[r0 + rl] * 64 + j], f2o(acc));   // rare boundary blocks
    }
    if (uni) {
        red[rq][j] = runmax;
        __syncthreads();
        if (tid < 64) {
            float m = fmaxf(fmaxf(red[0][tid], red[1][tid]), fmaxf(red[2][tid], red[3][tid]));
            atomicMax(&gbufu[gfirst * 64 + tid], f2o(m));
        }
    }
}

// ---------------- MLP head, single block ----------------
__global__ __launch_bounds__(256) void mlp_kernel(const unsigned* __restrict__ gbufu,
                                                  const float* __restrict__ Wl1, const float* __restrict__ bl1,
                                                  const float* __restrict__ Wl2, const float* __restrict__ bl2,
                                                  const float* __restrict__ Wl3, const float* __restrict__ bl3,
                                                  float* __restrict__ out) {
    __shared__ float A[64][64];
    __shared__ float B[64][128];
    int tid = threadIdx.x;
    for (int idx = tid; idx < 64 * 64; idx += 256) A[idx >> 6][idx & 63] = o2f(gbufu[idx]);
    __syncthreads();
    {
        int j = tid & 127;
        int rg = tid >> 7;
        float wc[64];
        #pragma unroll
        for (int k = 0; k < 64; k++) wc[k] = Wl1[k * 128 + j];
        float bj = bl1[j];
        for (int r = rg; r < 64; r += 2) {
            float acc = bj;
            #pragma unroll
            for (int kc = 0; kc < 64; kc += 4) {
                float4 av = *(const float4*)&A[r][kc];
                acc += av.x * wc[kc] + av.y * wc[kc + 1] + av.z * wc[kc + 2] + av.w * wc[kc + 3];
            }
            B[r][j] = acc > 0.f ? acc : 0.1f * acc;
        }
    }
    __syncthreads();
    {
        int j = tid & 63;
        int rg = tid >> 6;
        float wc[128];
        #pragma unroll
        for (int k = 0; k < 128; k++) wc[k] = Wl2[k * 64 + j];
        float bj = bl2[j];
        for (int r = rg; r < 64; r += 4) {
            float acc = bj;
            #pragma unroll
            for (int kc = 0; kc < 128; kc += 4) {
                float4 bv = *(const float4*)&B[r][kc];
                acc += bv.x * wc[kc] + bv.y * wc[kc + 1] + bv.z * wc[kc + 2] + bv.w * wc[kc + 3];
            }
            A[r][j] = acc > 0.f ? acc : 0.1f * acc;
        }
    }
    __syncthreads();
    if (tid < 64) {
        int r = tid;
        float acc = bl3[0];
        #pragma unroll
        for (int k = 0; k < 64; k++) acc += A[r][k] * Wl3[k];
        out[r] = acc;
    }
}

extern "C" void kernel_launch(void* const* d_in, const int* in_sizes, int n_in,
                              void* d_out, int out_size, void* d_ws, size_t ws_size,
                              hipStream_t stream) {
    (void)in_sizes; (void)n_in; (void)out_size; (void)ws_size;
    const float* x    = (const float*)d_in[0];
    const int*   edge = (const int*)d_in[1];
    const int*   batch= (const int*)d_in[2];
    const float* W1   = (const float*)d_in[3];
    const float* b1   = (const float*)d_in[4];
    const float* W2   = (const float*)d_in[5];
    const float* b2   = (const float*)d_in[6];
    const float* Wl1  = (const float*)d_in[7];
    const float* bl1  = (const float*)d_in[8];
    const float* Wl2  = (const float*)d_in[9];
    const float* bl2  = (const float*)d_in[10];
    const float* Wl3  = (const float*)d_in[11];
    const float* bl3  = (const float*)d_in[12];
    const int* srcp = edge;
    const int* dstp = edge + N_EDGES;

    // workspace layout: zeroed region first = bucketCursor[NB] + gbufu[64*64] -> one tiny memset
    char* ws = (char*)d_ws;
    int*      bucketCursor = (int*)ws;
    unsigned* gbufu        = (unsigned*)(bucketCursor + NB);
    size_t zeroed = (size_t)(NB + N_GRAPHS * 64) * 4;
    size_t off = (zeroed + 255) & ~(size_t)255;
    auto alloc = [&](size_t bytes) { char* p = ws + off; off = (off + bytes + 255) & ~(size_t)255; return p; };
    float*    dis    = (float*)alloc((size_t)N_NODES * 4);
    int*      cnt    = (int*)alloc((size_t)N_NODES * 4);
    int*      rowptr = (int*)alloc((size_t)N_NODES * 4);
    unsigned* ebuf   = (unsigned*)alloc((size_t)NB * CAP * 4);   // bucketed packed edges, 8.6 MB
    int*      colb   = (int*)alloc((size_t)NB * CAP * 4);        // CSR columns (slab layout), 8.6 MB
    __half*   hs1a   = (__half*)alloc((size_t)N_NODES * 16 * 2); // feature-split halves, 3.2 MB each
    __half*   hs1b   = (__half*)alloc((size_t)N_NODES * 16 * 2);
    __half*   t1a    = (__half*)alloc((size_t)N_NODES * 16 * 2);
    __half*   t1b    = (__half*)alloc((size_t)N_NODES * 16 * 2);
    float*    agg32  = (float*)alloc((size_t)N_NODES * 32 * 4);

    hipMemsetAsync(ws, 0, zeroed, stream);

    bucket_kernel<<<500, 256, 0, stream>>>(srcp, dstp, bucketCursor, ebuf);
    csr_kernel   <<<NB, 256, 0, stream>>>(ebuf, bucketCursor, colb, rowptr, cnt, dis);
    gemm1_kernel <<<(N_NODES + 127) / 128, 256, 0, stream>>>(x, W1, dis, hs1a, hs1b);
    // agg layer 1: two L2-resident passes (3.2 MB gather buffers)
    aggL1_kernel <<<6250, 256, 0, stream>>>(hs1a, colb, rowptr, cnt, dis, b1,      t1a);
    aggL1_kernel <<<6250, 256, 0, stream>>>(hs1b, colb, rowptr, cnt, dis, b1 + 16, t1b);
    // agg layer 2: two passes writing disjoint halves of interleaved agg32
    aggL2_kernel <<<6250, 256, 0, stream>>>(t1a, colb, rowptr, cnt, dis, agg32);
    aggL2_kernel <<<6250, 256, 0, stream>>>(t1b, colb, rowptr, cnt, dis, agg32 + 16);
    gemm2p_kernel<<<(N_NODES + 63) / 64, 256, 0, stream>>>(agg32, W2, b2, batch, gbufu);
    mlp_kernel   <<<1, 256, 0, stream>>>(gbufu, Wl1, bl1, Wl2, bl2, Wl3, bl3, (float*)d_out);
}